// Round 4
// baseline (333.855 us; speedup 1.0000x reference)
//
#include <hip/hip_runtime.h>
#include <math.h>

typedef __attribute__((ext_vector_type(8))) short short8;
typedef __attribute__((ext_vector_type(4))) float f32x4;
typedef __attribute__((ext_vector_type(4))) unsigned short ushort4v;

#define D_MODEL 768
#define NH      12
#define DK      64
#define SEQ     1024
#define NB      8
#define MTOT    (NB*SEQ)                  // 8192
#define NELT    ((size_t)MTOT*D_MODEL)    // 6291456
#define WELT    ((size_t)D_MODEL*D_MODEL) // 589824

__device__ __forceinline__ unsigned short f2bf(float f) {
    unsigned int u = __builtin_bit_cast(unsigned int, f);
    unsigned int r = (u + 0x7FFFu + ((u >> 16) & 1u)) >> 16;   // RNE
    return (unsigned short)r;
}
__device__ __forceinline__ float bf2f(unsigned short h) {
    return __builtin_bit_cast(float, ((unsigned int)h) << 16);
}
__device__ __forceinline__ void gload_lds16(const void* g, void* lds) {
    __builtin_amdgcn_global_load_lds(
        (const __attribute__((address_space(1))) unsigned int*)g,
        (__attribute__((address_space(3))) unsigned int*)lds, 16, 0, 0);
}

// ---------------------------------------------------------------------------
// fp32 -> bf16 converts
// ---------------------------------------------------------------------------
__global__ __launch_bounds__(256) void cvt3(
    const float* __restrict__ a, const float* __restrict__ b, const float* __restrict__ c,
    unsigned short* __restrict__ oa, unsigned short* __restrict__ ob, unsigned short* __restrict__ oc)
{
    size_t i = (size_t)blockIdx.x * 256 + threadIdx.x;
    const size_t per = NELT / 8;
    const float* s; unsigned short* d; size_t l;
    if (i < per)            { s = a; d = oa; l = i; }
    else if (i < 2*per)     { s = b; d = ob; l = i - per; }
    else                    { s = c; d = oc; l = i - 2*per; }
    const float4* sp = (const float4*)(s + l*8);
    float4 v0 = sp[0], v1 = sp[1];
    short8 o;
    o[0]=(short)f2bf(v0.x); o[1]=(short)f2bf(v0.y); o[2]=(short)f2bf(v0.z); o[3]=(short)f2bf(v0.w);
    o[4]=(short)f2bf(v1.x); o[5]=(short)f2bf(v1.y); o[6]=(short)f2bf(v1.z); o[7]=(short)f2bf(v1.w);
    *(short8*)(d + l*8) = o;
}

__global__ __launch_bounds__(256) void cvt4(
    const float* __restrict__ a, const float* __restrict__ b,
    const float* __restrict__ c, const float* __restrict__ e,
    unsigned short* __restrict__ oa, unsigned short* __restrict__ ob,
    unsigned short* __restrict__ oc, unsigned short* __restrict__ oe)
{
    size_t i = (size_t)blockIdx.x * 256 + threadIdx.x;
    const size_t per = WELT / 8;
    const float* s; unsigned short* d; size_t l;
    if (i < per)        { s = a; d = oa; l = i; }
    else if (i < 2*per) { s = b; d = ob; l = i - per; }
    else if (i < 3*per) { s = c; d = oc; l = i - 2*per; }
    else                { s = e; d = oe; l = i - 3*per; }
    const float4* sp = (const float4*)(s + l*8);
    float4 v0 = sp[0], v1 = sp[1];
    short8 o;
    o[0]=(short)f2bf(v0.x); o[1]=(short)f2bf(v0.y); o[2]=(short)f2bf(v0.z); o[3]=(short)f2bf(v0.w);
    o[4]=(short)f2bf(v1.x); o[5]=(short)f2bf(v1.y); o[6]=(short)f2bf(v1.z); o[7]=(short)f2bf(v1.w);
    *(short8*)(d + l*8) = o;
}

// ---------------------------------------------------------------------------
// bf16 MFMA GEMM: C = A @ W^T + bias.  A:[8192][768], W:[768][768] (row-major).
// MODE 0: bf16 row-major [8192][768], value = (acc+bias)*scale
// MODE 1: bf16 V^T layout [B,H,DK,SEQ]
// MODE 2: fp32 row-major [8192][768] + bias
// ---------------------------------------------------------------------------
#define BM 128
#define BN 128
#define BKG 64

template<int MODE>
__global__ __launch_bounds__(256) void gemm_bf16(
    const unsigned short* __restrict__ A, const unsigned short* __restrict__ W,
    const float* __restrict__ bias, void* __restrict__ Cout, float scale)
{
    __shared__ unsigned short As[BM*BKG];
    __shared__ unsigned short Bs[BN*BKG];
    const int tid = threadIdx.x;
    const int lane = tid & 63, wid = tid >> 6;
    const int wr = wid >> 1, wc = wid & 1;
    const int m0 = blockIdx.y * BM, n0 = blockIdx.x * BN;

    f32x4 acc[4][4];
    #pragma unroll
    for (int i = 0; i < 4; ++i)
        #pragma unroll
        for (int j = 0; j < 4; ++j) acc[i][j] = (f32x4)(0.f);

    for (int k0 = 0; k0 < D_MODEL; k0 += BKG) {
        __syncthreads();
        #pragma unroll
        for (int j = 0; j < 4; ++j) {
            int p = ((wid*4 + j) << 9) + lane*8;
            int row = p >> 6, off = p & 63;
            const unsigned short* srcA = A + (size_t)(m0+row)*D_MODEL + k0 + (off ^ ((row&7)<<3));
            gload_lds16(srcA, &As[(wid*4 + j) << 9]);
            const unsigned short* srcB = W + (size_t)(n0+row)*D_MODEL + k0 + (off ^ ((row&7)<<3));
            gload_lds16(srcB, &Bs[(wid*4 + j) << 9]);
        }
        __syncthreads();
        #pragma unroll
        for (int ks = 0; ks < 2; ++ks) {
            short8 af[4], bf8[4];
            #pragma unroll
            for (int mi = 0; mi < 4; ++mi) {
                int row = wr*64 + mi*16 + (lane & 15);
                af[mi] = *(const short8*)&As[row*BKG + ((ks*32 + (lane>>4)*8) ^ ((row&7)<<3))];
            }
            #pragma unroll
            for (int ni = 0; ni < 4; ++ni) {
                int row = wc*64 + ni*16 + (lane & 15);
                bf8[ni] = *(const short8*)&Bs[row*BKG + ((ks*32 + (lane>>4)*8) ^ ((row&7)<<3))];
            }
            #pragma unroll
            for (int mi = 0; mi < 4; ++mi)
                #pragma unroll
                for (int ni = 0; ni < 4; ++ni)
                    acc[mi][ni] = __builtin_amdgcn_mfma_f32_16x16x32_bf16(af[mi], bf8[ni], acc[mi][ni], 0, 0, 0);
        }
    }

    float bv[4];
    #pragma unroll
    for (int ni = 0; ni < 4; ++ni) bv[ni] = bias[n0 + wc*64 + ni*16 + (lane & 15)];

    if (MODE == 0) {
        unsigned short* C = (unsigned short*)Cout;
        #pragma unroll
        for (int mi = 0; mi < 4; ++mi)
            #pragma unroll
            for (int ni = 0; ni < 4; ++ni) {
                int col = n0 + wc*64 + ni*16 + (lane & 15);
                int rbase = m0 + wr*64 + mi*16 + ((lane>>4)<<2);
                #pragma unroll
                for (int j = 0; j < 4; ++j)
                    C[(size_t)(rbase+j)*D_MODEL + col] = f2bf((acc[mi][ni][j] + bv[ni]) * scale);
            }
    } else if (MODE == 1) {
        unsigned short* C = (unsigned short*)Cout;
        #pragma unroll
        for (int mi = 0; mi < 4; ++mi)
            #pragma unroll
            for (int ni = 0; ni < 4; ++ni) {
                int col = n0 + wc*64 + ni*16 + (lane & 15);
                int hh = col >> 6, dd = col & 63;
                int m = m0 + wr*64 + mi*16 + ((lane>>4)<<2);
                int bb = m >> 10, ss = m & (SEQ-1);
                ushort4v pk;
                #pragma unroll
                for (int j = 0; j < 4; ++j) pk[j] = f2bf(acc[mi][ni][j] + bv[ni]);
                *(ushort4v*)&C[((size_t)(bb*NH + hh)*DK + dd)*SEQ + ss] = pk;
            }
    } else {
        float* C = (float*)Cout;
        #pragma unroll
        for (int mi = 0; mi < 4; ++mi)
            #pragma unroll
            for (int ni = 0; ni < 4; ++ni) {
                int col = n0 + wc*64 + ni*16 + (lane & 15);
                int rbase = m0 + wr*64 + mi*16 + ((lane>>4)<<2);
                #pragma unroll
                for (int j = 0; j < 4; ++j)
                    C[(size_t)(rbase+j)*D_MODEL + col] = acc[mi][ni][j] + bv[ni];
            }
    }
}

// ---------------------------------------------------------------------------
// K~ precompute: fold the 3x3 conv into the K side.
//   C_a[k] = sum_b w[a,b] * K[k+b-1]  (zero padded)
//   Ktil[k] = [ K[k]-C_1[k] | -C_0[k] | -C_2[k] ]  in R^192
// so t[q,k] = Q[q]·Ktil[k][0:64] + Q[q-1]·Ktil[k][64:128] + Q[q+1]·Ktil[k][128:192]
// ---------------------------------------------------------------------------
__global__ __launch_bounds__(256) void kprep(
    const unsigned short* __restrict__ Kp,   // [B,S,768] bf16
    const float* __restrict__ CW,
    unsigned short* __restrict__ Ktil)       // [96][1024][192] bf16
{
    const int bh = blockIdx.x;
    const int h = bh % NH, b = bh / NH;
    const int kc = blockIdx.y;               // 8 chunks of 128 keys
    float w[9];
    #pragma unroll
    for (int i = 0; i < 9; ++i) w[i] = CW[h*9 + i];

    for (int t = threadIdx.x; t < 1024; t += 256) {
        int kl = t >> 3, oct = t & 7;
        int k = kc*128 + kl;
        const size_t base = (size_t)b*SEQ*D_MODEL + h*DK + oct*8;
        float km1[8], k0[8], kp1[8];
        if (k > 0) {
            short8 x = *(const short8*)&Kp[base + (size_t)(k-1)*D_MODEL];
            #pragma unroll
            for (int j = 0; j < 8; ++j) km1[j] = bf2f((unsigned short)x[j]);
        } else {
            #pragma unroll
            for (int j = 0; j < 8; ++j) km1[j] = 0.f;
        }
        {
            short8 x = *(const short8*)&Kp[base + (size_t)k*D_MODEL];
            #pragma unroll
            for (int j = 0; j < 8; ++j) k0[j] = bf2f((unsigned short)x[j]);
        }
        if (k < SEQ-1) {
            short8 x = *(const short8*)&Kp[base + (size_t)(k+1)*D_MODEL];
            #pragma unroll
            for (int j = 0; j < 8; ++j) kp1[j] = bf2f((unsigned short)x[j]);
        } else {
            #pragma unroll
            for (int j = 0; j < 8; ++j) kp1[j] = 0.f;
        }
        short8 o0, o1, o2;
        #pragma unroll
        for (int j = 0; j < 8; ++j) {
            float c0 = w[0]*km1[j] + w[1]*k0[j] + w[2]*kp1[j];
            float c1 = w[3]*km1[j] + w[4]*k0[j] + w[5]*kp1[j];
            float c2 = w[6]*km1[j] + w[7]*k0[j] + w[8]*kp1[j];
            o0[j] = (short)f2bf(k0[j] - c1);
            o1[j] = (short)f2bf(-c0);
            o2[j] = (short)f2bf(-c2);
        }
        size_t ob = ((size_t)bh*SEQ + k)*192 + oct*8;
        *(short8*)&Ktil[ob]       = o0;
        *(short8*)&Ktil[ob + 64]  = o1;
        *(short8*)&Ktil[ob + 128] = o2;
    }
}

// ---------------------------------------------------------------------------
// Fused attention, conv pre-folded into Ktil. Block = (b,h) x 32 q-rows,
// 8 waves. t = Qtil @ Ktil^T via MFMA (A-slots = row-shifted Q reads),
// then plain softmax, then PV with V^T chunks.
// ---------------------------------------------------------------------------
__global__ __launch_bounds__(512) void attn_lin(
    const unsigned short* __restrict__ Qp,   // [8192][768] bf16, scale folded
    const unsigned short* __restrict__ Ktil, // [96][1024][192] bf16
    const unsigned short* __restrict__ Vt,   // [96][64][1024] bf16
    unsigned short* __restrict__ Aop)        // [8192][768] bf16
{
    __shared__ unsigned short Ss[32*1024];   // 64 KB scores -> probs
    __shared__ unsigned short KVs[128*192];  // 48 KB: Ktil chunk / Vt chunk
    __shared__ unsigned short Qs[34*64];     // rows q0-1 .. q0+32

    const int tid = threadIdx.x;
    const int lane = tid & 63, wid = tid >> 6;
    const int q0 = blockIdx.x * 32;
    const int bh = blockIdx.y;
    const int h = bh % NH, b = bh / NH;

    // stage Q rows q0-1 .. q0+32 (zero OOB), swizzled
    if (tid < 272) {
        int row = tid >> 3, oct = tid & 7;
        int g = q0 - 1 + row;
        short8 val = (short8)0;
        if (g >= 0 && g < SEQ)
            val = *(const short8*)&Qp[(size_t)(b*SEQ + g)*D_MODEL + h*DK + oct*8];
        *(short8*)&Qs[row*64 + ((oct ^ (row&7)) << 3)] = val;
    }

    const char* KtB = (const char*)(Ktil + (size_t)bh*SEQ*192);
    const int mw = wid >> 2, nw = wid & 3;       // 2 x 4 wave grid for QK

    // Ktil slot s pairing: slot0 = K-C1 pairs Q[q] (Qs idx i+1),
    // slot1 = -C0 pairs Q[q-1] (idx i), slot2 = -C2 pairs Q[q+1] (idx i+2).
    const int ashift[3] = {1, 0, 2};

    // ---- QK~^T over 8 chunks of 128 keys ----
    for (int ck = 0; ck < 8; ++ck) {
        __syncthreads();
        #pragma unroll
        for (int j = 0; j < 6; ++j) {
            int slice = wid*6 + j;
            int p = slice*1024 + lane*16;        // linear byte pos in 48 KB
            int row = p / 384, off = p - row*384;
            const char* src = KtB + (size_t)(ck*128 + row)*384 + (off ^ ((row&7)<<4));
            gload_lds16(src, (char*)KVs + slice*1024);
        }
        __syncthreads();

        f32x4 sacc[2];
        sacc[0] = (f32x4)(0.f); sacc[1] = (f32x4)(0.f);
        #pragma unroll
        for (int s = 0; s < 3; ++s)
            #pragma unroll
            for (int ks = 0; ks < 2; ++ks) {
                int arow = mw*16 + (lane & 15) + ashift[s];   // shifted Q row
                int aoct = ks*4 + (lane >> 4);
                short8 a8 = *(const short8*)&Qs[arow*64 + ((aoct ^ (arow&7)) << 3)];
                #pragma unroll
                for (int ni = 0; ni < 2; ++ni) {
                    int brow = nw*32 + ni*16 + (lane & 15);
                    int boct = s*8 + ks*4 + (lane >> 4);
                    short8 b8 = *(const short8*)&KVs[brow*192 + ((boct ^ (brow&7)) << 3)];
                    sacc[ni] = __builtin_amdgcn_mfma_f32_16x16x32_bf16(a8, b8, sacc[ni], 0, 0, 0);
                }
            }
        #pragma unroll
        for (int ni = 0; ni < 2; ++ni) {
            int col = ck*128 + nw*32 + ni*16 + (lane & 15);
            #pragma unroll
            for (int j = 0; j < 4; ++j) {
                int row = mw*16 + ((lane>>4)<<2) + j;
                Ss[row*1024 + (col ^ ((row&7)<<3))] = f2bf(sacc[ni][j]);
            }
        }
    }
    __syncthreads();

    // ---- softmax: wave owns rows wid*4..wid*4+3; 16 cols per lane ----
    #pragma unroll
    for (int rr = 0; rr < 4; ++rr) {
        int row = wid*4 + rr;
        int oA = lane*2, oB = lane*2 + 1;
        short8 v0 = *(const short8*)&Ss[row*1024 + ((oA ^ (row&7)) << 3)];
        short8 v1 = *(const short8*)&Ss[row*1024 + ((oB ^ (row&7)) << 3)];
        float t[16], tmax = -1e30f;
        #pragma unroll
        for (int i = 0; i < 8; ++i) {
            t[i]   = bf2f((unsigned short)v0[i]);
            t[8+i] = bf2f((unsigned short)v1[i]);
        }
        #pragma unroll
        for (int i = 0; i < 16; ++i) tmax = fmaxf(tmax, t[i]);
        #pragma unroll
        for (int o = 1; o < 64; o <<= 1) tmax = fmaxf(tmax, __shfl_xor(tmax, o));
        float p[16], lsum = 0.f;
        #pragma unroll
        for (int i = 0; i < 16; ++i) { p[i] = __expf(t[i] - tmax); lsum += p[i]; }
        #pragma unroll
        for (int o = 1; o < 64; o <<= 1) lsum += __shfl_xor(lsum, o);
        float inv = 1.0f / lsum;
        short8 w0, w1;
        #pragma unroll
        for (int i = 0; i < 8; ++i) {
            w0[i] = (short)f2bf(p[i] * inv);
            w1[i] = (short)f2bf(p[8+i] * inv);
        }
        *(short8*)&Ss[row*1024 + ((oA ^ (row&7)) << 3)] = w0;
        *(short8*)&Ss[row*1024 + ((oB ^ (row&7)) << 3)] = w1;
    }
    __syncthreads();

    // ---- PV: O[32x64] = P[32x1024] @ V[1024x64], V^T chunks of 256 keys ----
    const int mw2 = wid >> 2, nw2 = wid & 3;
    f32x4 oacc = (f32x4)(0.f);
    for (int ck = 0; ck < 4; ++ck) {
        if (ck) __syncthreads();
        #pragma unroll
        for (int j = 0; j < 4; ++j) {
            int slice = wid*4 + j;
            int p = slice*1024 + lane*16;
            int row = p >> 9, off = p & 511;     // 512 B per Vt-chunk row
            const char* src = (const char*)Vt
                + ((size_t)(bh*DK + row)*SEQ + ck*256)*2 + (off ^ ((row&7)<<4));
            gload_lds16(src, (char*)KVs + slice*1024);
        }
        __syncthreads();
        #pragma unroll
        for (int ks = 0; ks < 8; ++ks) {
            int prow_ = mw2*16 + (lane & 15);
            int poct = ck*32 + ks*4 + (lane >> 4);
            short8 pa = *(const short8*)&Ss[prow_*1024 + ((poct ^ (prow_&7)) << 3)];
            int vrow = nw2*16 + (lane & 15);
            int voct = ks*4 + (lane >> 4);
            short8 vb8 = *(const short8*)&KVs[vrow*256 + ((voct ^ (vrow&7)) << 3)];
            oacc = __builtin_amdgcn_mfma_f32_16x16x32_bf16(pa, vb8, oacc, 0, 0, 0);
        }
    }
    {
        int col = h*DK + nw2*16 + (lane & 15);
        int mbase = q0 + mw2*16 + ((lane>>4)<<2);
        #pragma unroll
        for (int j = 0; j < 4; ++j)
            Aop[(size_t)(b*SEQ + mbase + j)*D_MODEL + col] = f2bf(oacc[j]);
    }
}

// ---------------------------------------------------------------------------
extern "C" void kernel_launch(void* const* d_in, const int* in_sizes, int n_in,
                              void* d_out, int out_size, void* d_ws, size_t ws_size,
                              hipStream_t stream)
{
    const float* q  = (const float*)d_in[0];
    const float* k  = (const float*)d_in[1];
    const float* v  = (const float*)d_in[2];
    const float* wq = (const float*)d_in[3];
    const float* bq = (const float*)d_in[4];
    const float* wk = (const float*)d_in[5];
    const float* bk = (const float*)d_in[6];
    const float* wv = (const float*)d_in[7];
    const float* bv = (const float*)d_in[8];
    const float* wo = (const float*)d_in[9];
    const float* bo = (const float*)d_in[10];
    const float* cw = (const float*)d_in[11];

    unsigned short* qb  = (unsigned short*)d_ws;     // 3*NELT: inputs, then Ktil
    unsigned short* kb  = qb  + NELT;
    unsigned short* vb  = kb  + NELT;
    unsigned short* wqb = vb  + NELT;
    unsigned short* wkb = wqb + WELT;
    unsigned short* wvb = wkb + WELT;
    unsigned short* wob = wvb + WELT;
    unsigned short* Qp  = wob + WELT;
    unsigned short* Kp  = Qp  + NELT;
    unsigned short* Vtp = Kp  + NELT;
    unsigned short* Aop = Vtp + NELT;
    unsigned short* Ktil = qb;   // 96*1024*192 = 3*NELT exactly; inputs dead by then

    cvt3<<<(int)(3*NELT/8/256), 256, 0, stream>>>(q, k, v, qb, kb, vb);
    cvt4<<<(int)(4*WELT/8/256), 256, 0, stream>>>(wq, wk, wv, wo, wqb, wkb, wvb, wob);

    dim3 gg(D_MODEL/BN, MTOT/BM);   // (6, 64)
    gemm_bf16<0><<<gg, 256, 0, stream>>>(qb, wqb, bq, Qp, 0.125f);
    gemm_bf16<0><<<gg, 256, 0, stream>>>(kb, wkb, bk, Kp, 1.0f);
    gemm_bf16<1><<<gg, 256, 0, stream>>>(vb, wvb, bv, Vtp, 1.0f);

    kprep<<<dim3(NB*NH, 8), 256, 0, stream>>>(Kp, cw, Ktil);

    attn_lin<<<dim3(SEQ/32, NB*NH), 512, 0, stream>>>(Qp, Ktil, Vtp, Aop);

    gemm_bf16<2><<<gg, 256, 0, stream>>>(Aop, wob, bo, (float*)d_out, 1.0f);
}

// Round 6
// 290.302 us; speedup vs baseline: 1.1500x; 1.1500x over previous
//
#include <hip/hip_runtime.h>
#include <math.h>

typedef __attribute__((ext_vector_type(8))) short short8;
typedef __attribute__((ext_vector_type(4))) float f32x4;
typedef __attribute__((ext_vector_type(4))) unsigned short ushort4v;

#define D_MODEL 768
#define NH      12
#define DK      64
#define SEQ     1024
#define NB      8
#define MTOT    (NB*SEQ)                  // 8192
#define NELT    ((size_t)MTOT*D_MODEL)    // 6291456
#define WELT    ((size_t)D_MODEL*D_MODEL) // 589824

__device__ __forceinline__ unsigned short f2bf(float f) {
    unsigned int u = __builtin_bit_cast(unsigned int, f);
    unsigned int r = (u + 0x7FFFu + ((u >> 16) & 1u)) >> 16;   // RNE
    return (unsigned short)r;
}
__device__ __forceinline__ float bf2f(unsigned short h) {
    return __builtin_bit_cast(float, ((unsigned int)h) << 16);
}
__device__ __forceinline__ void gload_lds16(const void* g, void* lds) {
    __builtin_amdgcn_global_load_lds(
        (const __attribute__((address_space(1))) unsigned int*)g,
        (__attribute__((address_space(3))) unsigned int*)lds, 16, 0, 0);
}

// ---------------------------------------------------------------------------
// fp32 -> bf16 converts
// ---------------------------------------------------------------------------
__global__ __launch_bounds__(256) void cvt3(
    const float* __restrict__ a, const float* __restrict__ b, const float* __restrict__ c,
    unsigned short* __restrict__ oa, unsigned short* __restrict__ ob, unsigned short* __restrict__ oc)
{
    size_t i = (size_t)blockIdx.x * 256 + threadIdx.x;
    const size_t per = NELT / 8;
    const float* s; unsigned short* d; size_t l;
    if (i < per)            { s = a; d = oa; l = i; }
    else if (i < 2*per)     { s = b; d = ob; l = i - per; }
    else                    { s = c; d = oc; l = i - 2*per; }
    const float4* sp = (const float4*)(s + l*8);
    float4 v0 = sp[0], v1 = sp[1];
    short8 o;
    o[0]=(short)f2bf(v0.x); o[1]=(short)f2bf(v0.y); o[2]=(short)f2bf(v0.z); o[3]=(short)f2bf(v0.w);
    o[4]=(short)f2bf(v1.x); o[5]=(short)f2bf(v1.y); o[6]=(short)f2bf(v1.z); o[7]=(short)f2bf(v1.w);
    *(short8*)(d + l*8) = o;
}

__global__ __launch_bounds__(256) void cvt4(
    const float* __restrict__ a, const float* __restrict__ b,
    const float* __restrict__ c, const float* __restrict__ e,
    unsigned short* __restrict__ oa, unsigned short* __restrict__ ob,
    unsigned short* __restrict__ oc, unsigned short* __restrict__ oe)
{
    size_t i = (size_t)blockIdx.x * 256 + threadIdx.x;
    const size_t per = WELT / 8;
    const float* s; unsigned short* d; size_t l;
    if (i < per)        { s = a; d = oa; l = i; }
    else if (i < 2*per) { s = b; d = ob; l = i - per; }
    else if (i < 3*per) { s = c; d = oc; l = i - 2*per; }
    else                { s = e; d = oe; l = i - 3*per; }
    const float4* sp = (const float4*)(s + l*8);
    float4 v0 = sp[0], v1 = sp[1];
    short8 o;
    o[0]=(short)f2bf(v0.x); o[1]=(short)f2bf(v0.y); o[2]=(short)f2bf(v0.z); o[3]=(short)f2bf(v0.w);
    o[4]=(short)f2bf(v1.x); o[5]=(short)f2bf(v1.y); o[6]=(short)f2bf(v1.z); o[7]=(short)f2bf(v1.w);
    *(short8*)(d + l*8) = o;
}

// ---------------------------------------------------------------------------
// bf16 MFMA GEMM: C = A @ W^T + bias.  A:[8192][768], W:[768][768] (row-major).
// MODE 0: bf16 row-major [8192][768], value = (acc+bias)*scale
// MODE 1: bf16 V^T layout [B,H,DK,SEQ]
// MODE 2: fp32 row-major [8192][768] + bias
// ---------------------------------------------------------------------------
#define BM 128
#define BN 128
#define BKG 64

template<int MODE>
__global__ __launch_bounds__(256) void gemm_bf16(
    const unsigned short* __restrict__ A, const unsigned short* __restrict__ W,
    const float* __restrict__ bias, void* __restrict__ Cout, float scale)
{
    __shared__ unsigned short As[BM*BKG];
    __shared__ unsigned short Bs[BN*BKG];
    const int tid = threadIdx.x;
    const int lane = tid & 63, wid = tid >> 6;
    const int wr = wid >> 1, wc = wid & 1;
    const int m0 = blockIdx.y * BM, n0 = blockIdx.x * BN;

    f32x4 acc[4][4];
    #pragma unroll
    for (int i = 0; i < 4; ++i)
        #pragma unroll
        for (int j = 0; j < 4; ++j) acc[i][j] = (f32x4)(0.f);

    for (int k0 = 0; k0 < D_MODEL; k0 += BKG) {
        __syncthreads();
        #pragma unroll
        for (int j = 0; j < 4; ++j) {
            int p = ((wid*4 + j) << 9) + lane*8;
            int row = p >> 6, off = p & 63;
            const unsigned short* srcA = A + (size_t)(m0+row)*D_MODEL + k0 + (off ^ ((row&7)<<3));
            gload_lds16(srcA, &As[(wid*4 + j) << 9]);
            const unsigned short* srcB = W + (size_t)(n0+row)*D_MODEL + k0 + (off ^ ((row&7)<<3));
            gload_lds16(srcB, &Bs[(wid*4 + j) << 9]);
        }
        __syncthreads();
        #pragma unroll
        for (int ks = 0; ks < 2; ++ks) {
            short8 af[4], bf8[4];
            #pragma unroll
            for (int mi = 0; mi < 4; ++mi) {
                int row = wr*64 + mi*16 + (lane & 15);
                af[mi] = *(const short8*)&As[row*BKG + ((ks*32 + (lane>>4)*8) ^ ((row&7)<<3))];
            }
            #pragma unroll
            for (int ni = 0; ni < 4; ++ni) {
                int row = wc*64 + ni*16 + (lane & 15);
                bf8[ni] = *(const short8*)&Bs[row*BKG + ((ks*32 + (lane>>4)*8) ^ ((row&7)<<3))];
            }
            #pragma unroll
            for (int mi = 0; mi < 4; ++mi)
                #pragma unroll
                for (int ni = 0; ni < 4; ++ni)
                    acc[mi][ni] = __builtin_amdgcn_mfma_f32_16x16x32_bf16(af[mi], bf8[ni], acc[mi][ni], 0, 0, 0);
        }
    }

    float bv[4];
    #pragma unroll
    for (int ni = 0; ni < 4; ++ni) bv[ni] = bias[n0 + wc*64 + ni*16 + (lane & 15)];

    if (MODE == 0) {
        unsigned short* C = (unsigned short*)Cout;
        #pragma unroll
        for (int mi = 0; mi < 4; ++mi)
            #pragma unroll
            for (int ni = 0; ni < 4; ++ni) {
                int col = n0 + wc*64 + ni*16 + (lane & 15);
                int rbase = m0 + wr*64 + mi*16 + ((lane>>4)<<2);
                #pragma unroll
                for (int j = 0; j < 4; ++j)
                    C[(size_t)(rbase+j)*D_MODEL + col] = f2bf((acc[mi][ni][j] + bv[ni]) * scale);
            }
    } else if (MODE == 1) {
        unsigned short* C = (unsigned short*)Cout;
        #pragma unroll
        for (int mi = 0; mi < 4; ++mi)
            #pragma unroll
            for (int ni = 0; ni < 4; ++ni) {
                int col = n0 + wc*64 + ni*16 + (lane & 15);
                int hh = col >> 6, dd = col & 63;
                int m = m0 + wr*64 + mi*16 + ((lane>>4)<<2);
                int bb = m >> 10, ss = m & (SEQ-1);
                ushort4v pk;
                #pragma unroll
                for (int j = 0; j < 4; ++j) pk[j] = f2bf(acc[mi][ni][j] + bv[ni]);
                *(ushort4v*)&C[((size_t)(bb*NH + hh)*DK + dd)*SEQ + ss] = pk;
            }
    } else {
        float* C = (float*)Cout;
        #pragma unroll
        for (int mi = 0; mi < 4; ++mi)
            #pragma unroll
            for (int ni = 0; ni < 4; ++ni) {
                int col = n0 + wc*64 + ni*16 + (lane & 15);
                int rbase = m0 + wr*64 + mi*16 + ((lane>>4)<<2);
                #pragma unroll
                for (int j = 0; j < 4; ++j)
                    C[(size_t)(rbase+j)*D_MODEL + col] = acc[mi][ni][j] + bv[ni];
            }
    }
}

// ---------------------------------------------------------------------------
// Fused attention, conv folded into Q~ (built in-LDS):
//   t[q,k] = Q~0[q]·K[k] + Q~1[q]·K[k-1] + Q~2[q]·K[k+1]
//   Q~0 = Q - D1, Q~1 = -D0, Q~2 = -D2,  D_b[q] = sum_a w[a,b] Q[q+a-1]
// Block = (b,h) x 32 q-rows, 8 waves. K chunks (128 keys + halo) reg-staged
// double-buffered; V chunks (128 keys) gload_lds double-buffered.
// ---------------------------------------------------------------------------
__global__ __launch_bounds__(512) void attn_qfold(
    const unsigned short* __restrict__ Qp,   // [8192][768] bf16, scale folded
    const unsigned short* __restrict__ Kp,   // [8192][768] bf16
    const unsigned short* __restrict__ Vt,   // [96][64][1024] bf16
    const float* __restrict__ CW,
    unsigned short* __restrict__ Aop)        // [8192][768] bf16
{
    __shared__ unsigned short Ss[32*1024];   // 64 KB scores -> probs
    __shared__ unsigned short Qt[32*192];    // 12 KB Q~ (swizzled)
    __shared__ unsigned short Ks[2][130*64]; // 2 x 16.25 KB K chunk + halo
    __shared__ unsigned short Vs[2][64*128]; // 2 x 16 KB V^T chunk

    const int tid = threadIdx.x;
    const int lane = tid & 63, wid = tid >> 6;

    // XCD-aware bijective swizzle: 3072 blocks = 8 XCDs x 384
    const int bid = blockIdx.x;
    const int sw = (bid & 7) * 384 + (bid >> 3);
    const int q0 = (sw & 31) * 32;
    const int bh = sw >> 5;
    const int h = bh % NH, b = bh / NH;

    float wcv[9];
    #pragma unroll
    for (int i = 0; i < 9; ++i) wcv[i] = CW[h*9 + i];

    const unsigned short* KpB = Kp + (size_t)b*SEQ*D_MODEL + h*DK;

    // ---- K chunk stage: 130 rows (keys ck*128-1 .. ck*128+128) x 64 dims ----
    short8 kreg[3];
    auto kload = [&](int ck) {
        #pragma unroll
        for (int u = 0; u < 3; ++u) {
            int idx = tid + u*512;
            short8 val = (short8)0;
            if (idx < 1040) {
                int r = idx >> 3, oct = idx & 7;
                int gk = ck*128 - 1 + r;
                if (gk >= 0 && gk < SEQ)
                    val = *(const short8*)&KpB[(size_t)gk*D_MODEL + oct*8];
            }
            kreg[u] = val;
        }
    };
    auto kstore = [&](int buf) {
        #pragma unroll
        for (int u = 0; u < 3; ++u) {
            int idx = tid + u*512;
            if (idx < 1040) {
                int r = idx >> 3, oct = idx & 7;
                *(short8*)&Ks[buf][r*64 + ((oct ^ (r&7)) << 3)] = kreg[u];
            }
        }
    };

    kload(0);   // chunk-0 loads fly under Q~ build

    // ---- build Q~ [32 rows][192] in LDS ----
    if (tid < 256) {
        int row = tid >> 3, oct = tid & 7;
        int gq = q0 + row;
        const unsigned short* QpB = Qp + (size_t)b*SEQ*D_MODEL + h*DK + oct*8;
        short8 qm = (short8)0, q0v, qp = (short8)0;
        if (gq > 0)       qm = *(const short8*)&QpB[(size_t)(gq-1)*D_MODEL];
        q0v = *(const short8*)&QpB[(size_t)gq*D_MODEL];
        if (gq < SEQ-1)   qp = *(const short8*)&QpB[(size_t)(gq+1)*D_MODEL];
        short8 s0, s1, s2;
        #pragma unroll
        for (int j = 0; j < 8; ++j) {
            float fm = bf2f((unsigned short)qm[j]);
            float f0 = bf2f((unsigned short)q0v[j]);
            float fp = bf2f((unsigned short)qp[j]);
            float d0 = wcv[0]*fm + wcv[3]*f0 + wcv[6]*fp;
            float d1 = wcv[1]*fm + wcv[4]*f0 + wcv[7]*fp;
            float d2 = wcv[2]*fm + wcv[5]*f0 + wcv[8]*fp;
            s0[j] = (short)f2bf(f0 - d1);
            s1[j] = (short)f2bf(-d0);
            s2[j] = (short)f2bf(-d2);
        }
        *(short8*)&Qt[row*192 + (((0*8+oct) ^ (row&7)) << 3)] = s0;
        *(short8*)&Qt[row*192 + (((1*8+oct) ^ (row&7)) << 3)] = s1;
        *(short8*)&Qt[row*192 + (((2*8+oct) ^ (row&7)) << 3)] = s2;
    }

    kstore(0);          // waits on kload(0) vmcnt internally
    __syncthreads();

    const int mw = wid >> 2, nw = wid & 3;   // 2 x 4 wave grid

    // Q~ slot s pairs K-row shift bshift[s]: slot0 (Q-D1) -> K[k] (local kl+1),
    // slot1 (-D0) -> K[k-1] (kl+0), slot2 (-D2) -> K[k+1] (kl+2).
    const int bshift[3] = {1, 0, 2};

    // ---- QK~: 8 chunks of 128 keys, double-buffered, 1 barrier/chunk ----
    int cur = 0;
    for (int ck = 0; ck < 8; ++ck) {
        if (ck < 7) kload(ck+1);             // issue early; lands under MFMA

        f32x4 sacc[2];
        sacc[0] = (f32x4)(0.f); sacc[1] = (f32x4)(0.f);
        #pragma unroll
        for (int s = 0; s < 3; ++s)
            #pragma unroll
            for (int ks = 0; ks < 2; ++ks) {
                int arow = mw*16 + (lane & 15);
                int aoct = s*8 + ks*4 + (lane >> 4);
                short8 a8 = *(const short8*)&Qt[arow*192 + ((aoct ^ (arow&7)) << 3)];
                #pragma unroll
                for (int ni = 0; ni < 2; ++ni) {
                    int br = nw*32 + ni*16 + (lane & 15) + bshift[s];
                    int boct = ks*4 + (lane >> 4);
                    short8 b8 = *(const short8*)&Ks[cur][br*64 + ((boct ^ (br&7)) << 3)];
                    sacc[ni] = __builtin_amdgcn_mfma_f32_16x16x32_bf16(a8, b8, sacc[ni], 0, 0, 0);
                }
            }
        #pragma unroll
        for (int ni = 0; ni < 2; ++ni) {
            int col = ck*128 + nw*32 + ni*16 + (lane & 15);
            #pragma unroll
            for (int j = 0; j < 4; ++j) {
                int row = mw*16 + ((lane>>4)<<2) + j;
                Ss[row*1024 + (col ^ ((row&7)<<3))] = f2bf(sacc[ni][j]);
            }
        }
        if (ck < 7) kstore(cur ^ 1);
        __syncthreads();
        cur ^= 1;
    }

    // ---- prefetch V chunk 0 under softmax ----
    const char* VtB = (const char*)Vt + (size_t)bh*DK*SEQ*2;
    auto vstage = [&](int ck, int buf) {
        #pragma unroll
        for (int j = 0; j < 2; ++j) {
            int slice = wid*2 + j;
            int p = slice*1024 + lane*16;        // byte pos in 16 KB
            int row = p >> 8, off = p & 255;     // 256 B per d-row (128 keys)
            const char* src = VtB + ((size_t)row*SEQ + ck*128)*2 + (off ^ ((row&7)<<4));
            gload_lds16(src, (char*)Vs[buf] + slice*1024);
        }
    };
    vstage(0, 0);

    // ---- softmax: wave owns rows wid*4..wid*4+3; 16 cols per lane ----
    #pragma unroll
    for (int rr = 0; rr < 4; ++rr) {
        int row = wid*4 + rr;
        int oA = lane*2, oB = lane*2 + 1;
        short8 v0 = *(const short8*)&Ss[row*1024 + ((oA ^ (row&7)) << 3)];
        short8 v1 = *(const short8*)&Ss[row*1024 + ((oB ^ (row&7)) << 3)];
        float t[16], tmax = -1e30f;
        #pragma unroll
        for (int i = 0; i < 8; ++i) {
            t[i]   = bf2f((unsigned short)v0[i]);
            t[8+i] = bf2f((unsigned short)v1[i]);
        }
        #pragma unroll
        for (int i = 0; i < 16; ++i) tmax = fmaxf(tmax, t[i]);
        #pragma unroll
        for (int o = 1; o < 64; o <<= 1) tmax = fmaxf(tmax, __shfl_xor(tmax, o));
        float p[16], lsum = 0.f;
        #pragma unroll
        for (int i = 0; i < 16; ++i) { p[i] = __expf(t[i] - tmax); lsum += p[i]; }
        #pragma unroll
        for (int o = 1; o < 64; o <<= 1) lsum += __shfl_xor(lsum, o);
        float inv = 1.0f / lsum;
        short8 w0, w1;
        #pragma unroll
        for (int i = 0; i < 8; ++i) {
            w0[i] = (short)f2bf(p[i] * inv);
            w1[i] = (short)f2bf(p[8+i] * inv);
        }
        *(short8*)&Ss[row*1024 + ((oA ^ (row&7)) << 3)] = w0;
        *(short8*)&Ss[row*1024 + ((oB ^ (row&7)) << 3)] = w1;
    }
    __syncthreads();   // probs visible; V chunk 0 drained (vmcnt0 at barrier)

    // ---- PV: 8 chunks of 128 keys, double-buffered, 1 barrier/chunk ----
    const int mw2 = wid >> 2, nw2 = wid & 3;
    f32x4 oacc = (f32x4)(0.f);
    for (int ck = 0; ck < 8; ++ck) {
        if (ck < 7) vstage(ck+1, (ck+1) & 1);
        #pragma unroll
        for (int ks = 0; ks < 4; ++ks) {
            int prow_ = mw2*16 + (lane & 15);
            int poct = ck*16 + ks*4 + (lane >> 4);
            short8 pa = *(const short8*)&Ss[prow_*1024 + ((poct ^ (prow_&7)) << 3)];
            int vrow = nw2*16 + (lane & 15);
            int voct = ks*4 + (lane >> 4);
            short8 vb8 = *(const short8*)&Vs[ck & 1][vrow*128 + ((voct ^ (vrow&7)) << 3)];
            oacc = __builtin_amdgcn_mfma_f32_16x16x32_bf16(pa, vb8, oacc, 0, 0, 0);
        }
        __syncthreads();   // drains vmcnt -> next buffer ready; protects WAR
    }
    {
        int col = h*DK + nw2*16 + (lane & 15);
        int mbase = q0 + mw2*16 + ((lane>>4)<<2);
        #pragma unroll
        for (int j = 0; j < 4; ++j)
            Aop[(size_t)(b*SEQ + mbase + j)*D_MODEL + col] = f2bf(oacc[j]);
    }
}

// ---------------------------------------------------------------------------
extern "C" void kernel_launch(void* const* d_in, const int* in_sizes, int n_in,
                              void* d_out, int out_size, void* d_ws, size_t ws_size,
                              hipStream_t stream)
{
    const float* q  = (const float*)d_in[0];
    const float* k  = (const float*)d_in[1];
    const float* v  = (const float*)d_in[2];
    const float* wq = (const float*)d_in[3];
    const float* bq = (const float*)d_in[4];
    const float* wk = (const float*)d_in[5];
    const float* bk = (const float*)d_in[6];
    const float* wv = (const float*)d_in[7];
    const float* bv = (const float*)d_in[8];
    const float* wo = (const float*)d_in[9];
    const float* bo = (const float*)d_in[10];
    const float* cw = (const float*)d_in[11];

    unsigned short* qb  = (unsigned short*)d_ws;
    unsigned short* kb  = qb  + NELT;
    unsigned short* vb  = kb  + NELT;
    unsigned short* wqb = vb  + NELT;
    unsigned short* wkb = wqb + WELT;
    unsigned short* wvb = wkb + WELT;
    unsigned short* wob = wvb + WELT;
    unsigned short* Qp  = wob + WELT;
    unsigned short* Kp  = Qp  + NELT;
    unsigned short* Vtp = Kp  + NELT;
    unsigned short* Aop = Vtp + NELT;

    cvt3<<<(int)(3*NELT/8/256), 256, 0, stream>>>(q, k, v, qb, kb, vb);
    cvt4<<<(int)(4*WELT/8/256), 256, 0, stream>>>(wq, wk, wv, wo, wqb, wkb, wvb, wob);

    dim3 gg(D_MODEL/BN, MTOT/BM);   // (6, 64)
    gemm_bf16<0><<<gg, 256, 0, stream>>>(qb, wqb, bq, Qp, 0.125f);
    gemm_bf16<0><<<gg, 256, 0, stream>>>(kb, wkb, bk, Kp, 1.0f);
    gemm_bf16<1><<<gg, 256, 0, stream>>>(vb, wvb, bv, Vtp, 1.0f);

    attn_qfold<<<dim3(3072), 512, 0, stream>>>(Qp, Kp, Vtp, cw, Aop);

    gemm_bf16<2><<<gg, 256, 0, stream>>>(Aop, wob, bo, (float*)d_out, 1.0f);
}

// Round 7
// 172.625 us; speedup vs baseline: 1.9340x; 1.6817x over previous
//
#include <hip/hip_runtime.h>
#include <math.h>

typedef __attribute__((ext_vector_type(8))) short short8;
typedef __attribute__((ext_vector_type(4))) float f32x4;
typedef __attribute__((ext_vector_type(4))) unsigned short ushort4v;

#define D_MODEL 768
#define NH      12
#define DK      64
#define SEQ     1024
#define NB      8
#define MTOT    (NB*SEQ)                  // 8192
#define NELT    ((size_t)MTOT*D_MODEL)    // 6291456
#define WELT    ((size_t)D_MODEL*D_MODEL) // 589824

__device__ __forceinline__ unsigned short f2bf(float f) {
    unsigned int u = __builtin_bit_cast(unsigned int, f);
    unsigned int r = (u + 0x7FFFu + ((u >> 16) & 1u)) >> 16;   // RNE
    return (unsigned short)r;
}
__device__ __forceinline__ float bf2f(unsigned short h) {
    return __builtin_bit_cast(float, ((unsigned int)h) << 16);
}
__device__ __forceinline__ void gload_lds16(const void* g, void* lds) {
    __builtin_amdgcn_global_load_lds(
        (const __attribute__((address_space(1))) unsigned int*)g,
        (__attribute__((address_space(3))) unsigned int*)lds, 16, 0, 0);
}

// ---------------------------------------------------------------------------
// fp32 -> bf16 converts
// ---------------------------------------------------------------------------
__global__ __launch_bounds__(256) void cvt3(
    const float* __restrict__ a, const float* __restrict__ b, const float* __restrict__ c,
    unsigned short* __restrict__ oa, unsigned short* __restrict__ ob, unsigned short* __restrict__ oc)
{
    size_t i = (size_t)blockIdx.x * 256 + threadIdx.x;
    const size_t per = NELT / 8;
    const float* s; unsigned short* d; size_t l;
    if (i < per)            { s = a; d = oa; l = i; }
    else if (i < 2*per)     { s = b; d = ob; l = i - per; }
    else                    { s = c; d = oc; l = i - 2*per; }
    const float4* sp = (const float4*)(s + l*8);
    float4 v0 = sp[0], v1 = sp[1];
    short8 o;
    o[0]=(short)f2bf(v0.x); o[1]=(short)f2bf(v0.y); o[2]=(short)f2bf(v0.z); o[3]=(short)f2bf(v0.w);
    o[4]=(short)f2bf(v1.x); o[5]=(short)f2bf(v1.y); o[6]=(short)f2bf(v1.z); o[7]=(short)f2bf(v1.w);
    *(short8*)(d + l*8) = o;
}

__global__ __launch_bounds__(256) void cvt4(
    const float* __restrict__ a, const float* __restrict__ b,
    const float* __restrict__ c, const float* __restrict__ e,
    unsigned short* __restrict__ oa, unsigned short* __restrict__ ob,
    unsigned short* __restrict__ oc, unsigned short* __restrict__ oe)
{
    size_t i = (size_t)blockIdx.x * 256 + threadIdx.x;
    const size_t per = WELT / 8;
    const float* s; unsigned short* d; size_t l;
    if (i < per)        { s = a; d = oa; l = i; }
    else if (i < 2*per) { s = b; d = ob; l = i - per; }
    else if (i < 3*per) { s = c; d = oc; l = i - 2*per; }
    else                { s = e; d = oe; l = i - 3*per; }
    const float4* sp = (const float4*)(s + l*8);
    float4 v0 = sp[0], v1 = sp[1];
    short8 o;
    o[0]=(short)f2bf(v0.x); o[1]=(short)f2bf(v0.y); o[2]=(short)f2bf(v0.z); o[3]=(short)f2bf(v0.w);
    o[4]=(short)f2bf(v1.x); o[5]=(short)f2bf(v1.y); o[6]=(short)f2bf(v1.z); o[7]=(short)f2bf(v1.w);
    *(short8*)(d + l*8) = o;
}

// ---------------------------------------------------------------------------
// bf16 MFMA GEMM: C = A @ W^T + bias (unchanged, verified)
// ---------------------------------------------------------------------------
#define BM 128
#define BN 128
#define BKG 64

template<int MODE>
__global__ __launch_bounds__(256) void gemm_bf16(
    const unsigned short* __restrict__ A, const unsigned short* __restrict__ W,
    const float* __restrict__ bias, void* __restrict__ Cout, float scale)
{
    __shared__ unsigned short As[BM*BKG];
    __shared__ unsigned short Bs[BN*BKG];
    const int tid = threadIdx.x;
    const int lane = tid & 63, wid = tid >> 6;
    const int wr = wid >> 1, wc = wid & 1;
    const int m0 = blockIdx.y * BM, n0 = blockIdx.x * BN;

    f32x4 acc[4][4];
    #pragma unroll
    for (int i = 0; i < 4; ++i)
        #pragma unroll
        for (int j = 0; j < 4; ++j) acc[i][j] = (f32x4)(0.f);

    for (int k0 = 0; k0 < D_MODEL; k0 += BKG) {
        __syncthreads();
        #pragma unroll
        for (int j = 0; j < 4; ++j) {
            int p = ((wid*4 + j) << 9) + lane*8;
            int row = p >> 6, off = p & 63;
            const unsigned short* srcA = A + (size_t)(m0+row)*D_MODEL + k0 + (off ^ ((row&7)<<3));
            gload_lds16(srcA, &As[(wid*4 + j) << 9]);
            const unsigned short* srcB = W + (size_t)(n0+row)*D_MODEL + k0 + (off ^ ((row&7)<<3));
            gload_lds16(srcB, &Bs[(wid*4 + j) << 9]);
        }
        __syncthreads();
        #pragma unroll
        for (int ks = 0; ks < 2; ++ks) {
            short8 af[4], bf8[4];
            #pragma unroll
            for (int mi = 0; mi < 4; ++mi) {
                int row = wr*64 + mi*16 + (lane & 15);
                af[mi] = *(const short8*)&As[row*BKG + ((ks*32 + (lane>>4)*8) ^ ((row&7)<<3))];
            }
            #pragma unroll
            for (int ni = 0; ni < 4; ++ni) {
                int row = wc*64 + ni*16 + (lane & 15);
                bf8[ni] = *(const short8*)&Bs[row*BKG + ((ks*32 + (lane>>4)*8) ^ ((row&7)<<3))];
            }
            #pragma unroll
            for (int mi = 0; mi < 4; ++mi)
                #pragma unroll
                for (int ni = 0; ni < 4; ++ni)
                    acc[mi][ni] = __builtin_amdgcn_mfma_f32_16x16x32_bf16(af[mi], bf8[ni], acc[mi][ni], 0, 0, 0);
        }
    }

    float bv[4];
    #pragma unroll
    for (int ni = 0; ni < 4; ++ni) bv[ni] = bias[n0 + wc*64 + ni*16 + (lane & 15)];

    if (MODE == 0) {
        unsigned short* C = (unsigned short*)Cout;
        #pragma unroll
        for (int mi = 0; mi < 4; ++mi)
            #pragma unroll
            for (int ni = 0; ni < 4; ++ni) {
                int col = n0 + wc*64 + ni*16 + (lane & 15);
                int rbase = m0 + wr*64 + mi*16 + ((lane>>4)<<2);
                #pragma unroll
                for (int j = 0; j < 4; ++j)
                    C[(size_t)(rbase+j)*D_MODEL + col] = f2bf((acc[mi][ni][j] + bv[ni]) * scale);
            }
    } else if (MODE == 1) {
        unsigned short* C = (unsigned short*)Cout;
        #pragma unroll
        for (int mi = 0; mi < 4; ++mi)
            #pragma unroll
            for (int ni = 0; ni < 4; ++ni) {
                int col = n0 + wc*64 + ni*16 + (lane & 15);
                int hh = col >> 6, dd = col & 63;
                int m = m0 + wr*64 + mi*16 + ((lane>>4)<<2);
                int bb = m >> 10, ss = m & (SEQ-1);
                ushort4v pk;
                #pragma unroll
                for (int j = 0; j < 4; ++j) pk[j] = f2bf(acc[mi][ni][j] + bv[ni]);
                *(ushort4v*)&C[((size_t)(bb*NH + hh)*DK + dd)*SEQ + ss] = pk;
            }
    } else {
        float* C = (float*)Cout;
        #pragma unroll
        for (int mi = 0; mi < 4; ++mi)
            #pragma unroll
            for (int ni = 0; ni < 4; ++ni) {
                int col = n0 + wc*64 + ni*16 + (lane & 15);
                int rbase = m0 + wr*64 + mi*16 + ((lane>>4)<<2);
                #pragma unroll
                for (int j = 0; j < 4; ++j)
                    C[(size_t)(rbase+j)*D_MODEL + col] = acc[mi][ni][j] + bv[ni];
            }
    }
}

// ---------------------------------------------------------------------------
// Flash attention, conv folded into Q~, swapped-operand MFMA.
//   t^T[k][q] = sum_s K[k+ds]·Q~s[q],  Q~ built per-warp in regs.
//   C col = q = lane&15 -> softmax lane-local (+shfl 16/32).
//   O^T[d][q] = mfma(V^T-frag, P-frag) with P through 2KB/warp LDS.
// Block = 8 warps x 16 q-rows = 128 q. 16 chunks of 64 keys, online softmax.
// ---------------------------------------------------------------------------
#define KVB 64
#define NCH (SEQ/KVB)   // 16

__global__ __launch_bounds__(512, 4) void attn_flash(
    const unsigned short* __restrict__ Qp,   // [8192][768] bf16, scale folded
    const unsigned short* __restrict__ Kp,   // [8192][768] bf16
    const unsigned short* __restrict__ Vt,   // [96][64][1024] bf16
    const float* __restrict__ CW,
    unsigned short* __restrict__ Aop)        // [8192][768] bf16
{
    __shared__ unsigned short Ks[2][66*64];  // 16.5 KB (halo rows k-1..k+64)
    __shared__ unsigned short Vs[2][64*64];  // 16 KB  V^T chunk [64d][64k]
    __shared__ unsigned short UB[130*64];    // 16.25 KB: Qstage, then 8x2KB P

    const int tid = threadIdx.x;
    const int lane = tid & 63, wid = tid >> 6;
    const int lq = lane & 15, lg = lane >> 4;

    // XCD-aware bijective swizzle: 768 = 8 XCDs x 96
    const int bid = blockIdx.x;
    const int sw = (bid & 7) * 96 + (bid >> 3);
    const int q0 = (sw & 7) * 128;
    const int bh = sw >> 3;
    const int h = bh % NH, b = bh / NH;

    float wcv[9];
    #pragma unroll
    for (int i = 0; i < 9; ++i) wcv[i] = CW[h*9 + i];

    const unsigned short* KpB = Kp + (size_t)b*SEQ*D_MODEL + h*DK;
    const unsigned short* QpB = Qp + (size_t)b*SEQ*D_MODEL + h*DK;
    const char* VtB = (const char*)Vt + (size_t)bh*DK*SEQ*2;

    // ---- K chunk stage (66 rows = keys ck*64-1 .. ck*64+64), reg-staged ----
    short8 kr0, kr1;
    auto kload = [&](int ck) {
        { int r = tid >> 3, oct = tid & 7;
          int gk = ck*KVB - 1 + r;
          short8 v = (short8)0;
          if (gk >= 0 && gk < SEQ) v = *(const short8*)&KpB[(size_t)gk*D_MODEL + oct*8];
          kr0 = v; }
        if (tid < 16) {
          int r = 64 + (tid >> 3), oct = tid & 7;
          int gk = ck*KVB - 1 + r;
          short8 v = (short8)0;
          if (gk >= 0 && gk < SEQ) v = *(const short8*)&KpB[(size_t)gk*D_MODEL + oct*8];
          kr1 = v; }
    };
    auto kstore = [&](int buf) {
        { int r = tid >> 3, oct = tid & 7;
          *(short8*)&Ks[buf][r*64 + ((oct ^ (r&7)) << 3)] = kr0; }
        if (tid < 16) {
          int r = 64 + (tid >> 3), oct = tid & 7;
          *(short8*)&Ks[buf][r*64 + ((oct ^ (r&7)) << 3)] = kr1; }
    };
    // ---- V^T chunk stage via global_load_lds (linear dest, preswz src) ----
    auto vstage = [&](int ck, int buf) {
        int p = tid * 16;                 // byte pos in 8 KB
        int row = p >> 7, off = p & 127;  // 128 B per d-row (64 keys)
        const char* src = VtB + ((size_t)row*SEQ + ck*KVB)*2 + (off ^ ((row&7)<<4));
        gload_lds16(src, (char*)Vs[buf] + p);
    };

    kload(0);

    // ---- stage Q rows q0-1 .. q0+128 into UB (zero OOB) ----
    {
        short8 qs0 = (short8)0, qs1 = (short8)0, qs2 = (short8)0;
        int r0 = tid >> 3, o0 = tid & 7;
        int g0 = q0 - 1 + r0;
        if (g0 >= 0 && g0 < SEQ) qs0 = *(const short8*)&QpB[(size_t)g0*D_MODEL + o0*8];
        int r1 = (512 + tid) >> 3, o1 = tid & 7;
        int g1 = q0 - 1 + r1;
        if (g1 >= 0 && g1 < SEQ) qs1 = *(const short8*)&QpB[(size_t)g1*D_MODEL + o1*8];
        int r2 = 0, o2 = 0, g2 = -1;
        if (tid < 16) {
            r2 = (1024 + tid) >> 3; o2 = tid & 7;
            g2 = q0 - 1 + r2;
            if (g2 >= 0 && g2 < SEQ) qs2 = *(const short8*)&QpB[(size_t)g2*D_MODEL + o2*8];
        }
        *(short8*)&UB[r0*64 + ((o0 ^ (r0&7)) << 3)] = qs0;
        *(short8*)&UB[r1*64 + ((o1 ^ (r1&7)) << 3)] = qs1;
        if (tid < 16) *(short8*)&UB[r2*64 + ((o2 ^ (r2&7)) << 3)] = qs2;
    }
    __syncthreads();

    // ---- build Q~ B-fragments in regs: q = lane&15, d-octs ks*32+lg*8 ----
    short8 qtf0[2], qtf1[2], qtf2[2];
    {
        int r0 = wid*16 + lq;     // Qstage row of Q[q-1]
        #pragma unroll
        for (int ks = 0; ks < 2; ++ks) {
            int oct = ks*4 + lg;
            int ra = r0, rb = r0 + 1, rc = r0 + 2;
            short8 am = *(const short8*)&UB[ra*64 + ((oct ^ (ra&7)) << 3)];
            short8 ac = *(const short8*)&UB[rb*64 + ((oct ^ (rb&7)) << 3)];
            short8 ap = *(const short8*)&UB[rc*64 + ((oct ^ (rc&7)) << 3)];
            short8 f0, f1, f2;
            #pragma unroll
            for (int j = 0; j < 8; ++j) {
                float fm = bf2f((unsigned short)am[j]);
                float fc = bf2f((unsigned short)ac[j]);
                float fp = bf2f((unsigned short)ap[j]);
                float t0 = fc - (wcv[1]*fm + wcv[4]*fc + wcv[7]*fp);
                float t1 = -(wcv[0]*fm + wcv[3]*fc + wcv[6]*fp);
                float t2 = -(wcv[2]*fm + wcv[5]*fc + wcv[8]*fp);
                f0[j] = (short)f2bf(t0);
                f1[j] = (short)f2bf(t1);
                f2[j] = (short)f2bf(t2);
            }
            qtf0[ks] = f0; qtf1[ks] = f1; qtf2[ks] = f2;
        }
    }
    kstore(0);
    vstage(0, 0);
    __syncthreads();

    unsigned short* Pw = &UB[wid * 1024];   // per-warp [16 q][64 k]

    float m = -1e30f, l = 0.f;
    f32x4 oac[4];
    #pragma unroll
    for (int dt = 0; dt < 4; ++dt) oac[dt] = (f32x4)(0.f);

    int cur = 0;
    for (int ck = 0; ck < NCH; ++ck) {
        if (ck < NCH-1) { kload(ck+1); vstage(ck+1, cur^1); }

        // ---- QK~^T: 4 k-tiles of 16; slot pairing K[k+{0,-1,+1}] via halo ----
        f32x4 st[4];
        #pragma unroll
        for (int t = 0; t < 4; ++t) {
            f32x4 s = (f32x4)(0.f);
            #pragma unroll
            for (int ks = 0; ks < 2; ++ks) {
                int oct = ks*4 + lg;
                int ar0 = t*16 + lq + 1;   // slot0 (Q-D1) -> K[k]
                short8 a0 = *(const short8*)&Ks[cur][ar0*64 + ((oct ^ (ar0&7)) << 3)];
                s = __builtin_amdgcn_mfma_f32_16x16x32_bf16(a0, qtf0[ks], s, 0, 0, 0);
                int ar1 = t*16 + lq;       // slot1 (-D0) -> K[k-1]
                short8 a1 = *(const short8*)&Ks[cur][ar1*64 + ((oct ^ (ar1&7)) << 3)];
                s = __builtin_amdgcn_mfma_f32_16x16x32_bf16(a1, qtf1[ks], s, 0, 0, 0);
                int ar2 = t*16 + lq + 2;   // slot2 (-D2) -> K[k+1]
                short8 a2 = *(const short8*)&Ks[cur][ar2*64 + ((oct ^ (ar2&7)) << 3)];
                s = __builtin_amdgcn_mfma_f32_16x16x32_bf16(a2, qtf2[ks], s, 0, 0, 0);
            }
            st[t] = s;
        }

        // ---- online softmax (q = lane&15; lanes {l,l^16,l^32,l^48} share q) ----
        float tmax = -1e30f;
        #pragma unroll
        for (int t = 0; t < 4; ++t)
            #pragma unroll
            for (int j = 0; j < 4; ++j) tmax = fmaxf(tmax, st[t][j]);
        tmax = fmaxf(tmax, __shfl_xor(tmax, 16));
        tmax = fmaxf(tmax, __shfl_xor(tmax, 32));
        float mn = fmaxf(m, tmax);
        float r = __expf(m - mn);
        float lsum = 0.f;
        #pragma unroll
        for (int t = 0; t < 4; ++t)
            #pragma unroll
            for (int j = 0; j < 4; ++j) {
                float e = __expf(st[t][j] - mn);
                st[t][j] = e;
                lsum += e;
            }
        lsum += __shfl_xor(lsum, 16);
        lsum += __shfl_xor(lsum, 32);
        l = l * r + lsum;
        m = mn;
        #pragma unroll
        for (int dt = 0; dt < 4; ++dt)
            #pragma unroll
            for (int j = 0; j < 4; ++j) oac[dt][j] *= r;

        // ---- P -> per-warp LDS (k-consecutive packs), then PV ----
        #pragma unroll
        for (int t = 0; t < 4; ++t) {
            ushort4v pk;
            #pragma unroll
            for (int j = 0; j < 4; ++j) pk[j] = f2bf(st[t][j]);
            *(ushort4v*)&Pw[lq*64 + ((t*16 + lg*4) ^ ((lq&7)<<3))] = pk;
        }
        #pragma unroll
        for (int kk = 0; kk < 2; ++kk) {
            short8 p8 = *(const short8*)&Pw[lq*64 + ((kk*32 + lg*8) ^ ((lq&7)<<3))];
            #pragma unroll
            for (int dt = 0; dt < 4; ++dt) {
                int vr = dt*16 + lq;
                int voct = kk*4 + lg;
                short8 v8 = *(const short8*)&Vs[cur][vr*64 + ((voct ^ (vr&7)) << 3)];
                oac[dt] = __builtin_amdgcn_mfma_f32_16x16x32_bf16(v8, p8, oac[dt], 0, 0, 0);
            }
        }

        if (ck < NCH-1) kstore(cur^1);
        __syncthreads();
        cur ^= 1;
    }

    // ---- epilogue: O^T col = q = lane&15; divide by l; write 4x8B ----
    float invl = 1.0f / l;
    int qg = q0 + wid*16 + lq;
    #pragma unroll
    for (int dt = 0; dt < 4; ++dt) {
        ushort4v o;
        #pragma unroll
        for (int j = 0; j < 4; ++j) o[j] = f2bf(oac[dt][j] * invl);
        *(ushort4v*)&Aop[(size_t)(b*SEQ + qg)*D_MODEL + h*DK + dt*16 + lg*4] = o;
    }
}

// ---------------------------------------------------------------------------
extern "C" void kernel_launch(void* const* d_in, const int* in_sizes, int n_in,
                              void* d_out, int out_size, void* d_ws, size_t ws_size,
                              hipStream_t stream)
{
    const float* q  = (const float*)d_in[0];
    const float* k  = (const float*)d_in[1];
    const float* v  = (const float*)d_in[2];
    const float* wq = (const float*)d_in[3];
    const float* bq = (const float*)d_in[4];
    const float* wk = (const float*)d_in[5];
    const float* bk = (const float*)d_in[6];
    const float* wv = (const float*)d_in[7];
    const float* bv = (const float*)d_in[8];
    const float* wo = (const float*)d_in[9];
    const float* bo = (const float*)d_in[10];
    const float* cw = (const float*)d_in[11];

    unsigned short* qb  = (unsigned short*)d_ws;
    unsigned short* kb  = qb  + NELT;
    unsigned short* vb  = kb  + NELT;
    unsigned short* wqb = vb  + NELT;
    unsigned short* wkb = wqb + WELT;
    unsigned short* wvb = wkb + WELT;
    unsigned short* wob = wvb + WELT;
    unsigned short* Qp  = wob + WELT;
    unsigned short* Kp  = Qp  + NELT;
    unsigned short* Vtp = Kp  + NELT;
    unsigned short* Aop = Vtp + NELT;

    cvt3<<<(int)(3*NELT/8/256), 256, 0, stream>>>(q, k, v, qb, kb, vb);
    cvt4<<<(int)(4*WELT/8/256), 256, 0, stream>>>(wq, wk, wv, wo, wqb, wkb, wvb, wob);

    dim3 gg(D_MODEL/BN, MTOT/BM);   // (6, 64)
    gemm_bf16<0><<<gg, 256, 0, stream>>>(qb, wqb, bq, Qp, 0.125f);
    gemm_bf16<0><<<gg, 256, 0, stream>>>(kb, wkb, bk, Kp, 1.0f);
    gemm_bf16<1><<<gg, 256, 0, stream>>>(vb, wvb, bv, Vtp, 1.0f);

    attn_flash<<<dim3(768), 512, 0, stream>>>(Qp, Kp, Vtp, cw, Aop);

    gemm_bf16<2><<<gg, 256, 0, stream>>>(Aop, wob, bo, (float*)d_out, 1.0f);
}